// Round 14
// baseline (2168.679 us; speedup 1.0000x reference)
//
#include <hip/hip_runtime.h>
#include <hip/hip_bf16.h>
#include <stdint.h>

// Problem constants
#define T_STEPS 512
#define BATCH   64
#define IN_DIM  128
#define HID     1024
#define KTOT    (HID + IN_DIM)   // 1152
#define NWAVES  4
#define THREADS (NWAVES * 64)

// 4 independent batch-groups x 16 col-slices. WG = 16 batches x 64 cols.
// Wave w: 16 batches x 16 cols, W in VGPRs (36 frags = 144 regs).
// Group H tile (16 x 1024 bf16 = 32 KB) double-buffered in LDS, shared.
// NO FLAGS: consumers poll the DATA (sentinel ring); ping-pong 2-set poll.
#define NGRP    4
#define NSL     16               // col-slice WGs per group
#define NB      16               // batches per group
#define NKH     32               // recurrent K-steps (1024/32)
#define NKX     4                // X K-steps (128/32)
#define HBUF    32768            // one H LDS buffer
#define LDSB    73728            // W-stage scratch (also covers 2x32KB H)

#define RING    16               // comm ring slots (2 MB)
#define DCLR    4                // clear-ahead depth
#define SLOT    (BATCH * HID)    // 65536 bf16 = 128 KB per slot
#define SENT    0x7F7F7F7F      // bf16 pair 3.39e38, unreachable by tanh

typedef float f32x4 __attribute__((ext_vector_type(4)));
typedef int   i32x4 __attribute__((ext_vector_type(4)));
typedef short s16x8 __attribute__((ext_vector_type(8)));
typedef uint32_t u32x2 __attribute__((ext_vector_type(2)));

#define MFMA16 __builtin_amdgcn_mfma_f32_16x16x32_bf16

__device__ __forceinline__ uint32_t cvt_pk_bf16(float a, float b) {
    uint32_t r;
    asm("v_cvt_pk_bf16_f32 %0, %1, %2" : "=v"(r) : "v"(a), "v"(b));
    return r;   // low16 = bf16(a), high16 = bf16(b)
}

union frag_u { uint32_t u[4]; s16x8 s; };

__device__ __forceinline__ s16x8 pack_bf16x8(f32x4 a, f32x4 b) {
    frag_u f;
    f.u[0] = cvt_pk_bf16(a.x, a.y);
    f.u[1] = cvt_pk_bf16(a.z, a.w);
    f.u[2] = cvt_pk_bf16(b.x, b.y);
    f.u[3] = cvt_pk_bf16(b.z, b.w);
    return f.s;
}

__device__ __forceinline__ uint16_t f32_to_bf16(float v) {
    uint32_t u = __builtin_bit_cast(uint32_t, v);
    return (uint16_t)((u + 0x7FFFu + ((u >> 16) & 1u)) >> 16);
}

// fast tanh: 1 - 2/(e^{2x}+1); saturates correctly for |x| large
__device__ __forceinline__ float tanh_fast(float x) {
    float e = __expf(2.0f * x);
    return 1.0f - 2.0f * __builtin_amdgcn_rcpf(e + 1.0f);
}

__device__ __forceinline__ int imax(int a, int b) { return a > b ? a : b; }
__device__ __forceinline__ int max4(f32x4 v) {
    i32x4 a = __builtin_bit_cast(i32x4, v);
    return imax(imax(a.x, a.y), imax(a.z, a.w));
}

// issue 8 coherent 16B loads, stride 256 B (NO wait)
#define ISSUE8(D, P)                                                    \
    asm volatile(                                                       \
        "global_load_dwordx4 %0, %8, off sc0 sc1\n\t"                   \
        "global_load_dwordx4 %1, %8, off offset:256 sc0 sc1\n\t"        \
        "global_load_dwordx4 %2, %8, off offset:512 sc0 sc1\n\t"        \
        "global_load_dwordx4 %3, %8, off offset:768 sc0 sc1\n\t"        \
        "global_load_dwordx4 %4, %8, off offset:1024 sc0 sc1\n\t"       \
        "global_load_dwordx4 %5, %8, off offset:1280 sc0 sc1\n\t"       \
        "global_load_dwordx4 %6, %8, off offset:1536 sc0 sc1\n\t"       \
        "global_load_dwordx4 %7, %8, off offset:1792 sc0 sc1"           \
        : "=&v"(D[0]), "=&v"(D[1]), "=&v"(D[2]), "=&v"(D[3]),           \
          "=&v"(D[4]), "=&v"(D[5]), "=&v"(D[6]), "=&v"(D[7])            \
        : "v"(P)                                                        \
        : "memory")

#define SCAN8(D, M)                                                     \
    { M = (int)0x80000000;                                              \
      _Pragma("unroll")                                                 \
      for (int _i = 0; _i < 8; ++_i) M = imax(M, max4(D[_i])); }

__global__ void rnn_init_kernel(const float* __restrict__ H0,
                                uint16_t* __restrict__ comm) {
    // slot 0 of the ring holds bf16(H0), read by step t=0
    int i = blockIdx.x * 256 + threadIdx.x;
    for (int e = i; e < SLOT; e += 64 * 256)
        comm[e] = f32_to_bf16(H0[e]);
}

__global__ __launch_bounds__(THREADS, 1)
void rnn_seq_kernel(const float* __restrict__ X, const float* __restrict__ Wih,
                    const float* __restrict__ Whh, const float* __restrict__ bh,
                    float* __restrict__ out, uint16_t* __restrict__ comm)
{
    extern __shared__ char lds[];

    const int tid = threadIdx.x;
    const int grp = blockIdx.x >> 4;       // batch group 0..3
    const int p   = blockIdx.x & 15;       // col-slice 0..15
    const int lane = tid & 63, wv = tid >> 6;
    const int cb = lane & 15, kg = lane >> 4;
    const int hc0 = p * 64;                // WG's first col
    const int b   = grp * NB + cb;         // batch row this lane owns

    // ---- One-time: load this wave's W (16 cols x 1152) into 36 reg frags.
    // Two-phase LDS bounce (fragment order, lane-linear, bijective).
    s16x8 wreg[36];
    #pragma unroll
    for (int half = 0; half < 2; ++half) {
        for (int e = tid; e < 32 * KTOT; e += THREADS) {
            int c2 = e & 31;
            int k  = e >> 5;
            int hcol = hc0 + half * 32 + c2;
            float w = (k < HID) ? Whh[(size_t)k * HID + hcol]
                                : Wih[(size_t)(k - HID) * HID + hcol];
            uint32_t off = ((uint32_t)((c2 >> 4) * 36 + (k >> 5)) << 10)
                         + (((k >> 3) & 3) << 8) + ((c2 & 15) << 4) + ((k & 7) << 1);
            *(uint16_t*)(lds + off) = f32_to_bf16(w);
        }
        __syncthreads();
        if ((wv >> 1) == half) {
            const char* base = lds + (size_t)(wv & 1) * 36 * 1024 + lane * 16;
            #pragma unroll
            for (int kk = 0; kk < 36; ++kk)
                wreg[kk] = *(const s16x8*)(base + (size_t)kk * 1024);
        }
        __syncthreads();
    }

    // D = mfma(Wfrag, Hfrag): rows = h, cols = batch. Lane owns
    // h = hc0 + wv*16 + kg*4 + {0..3} of batch b.
    const int h = hc0 + wv * 16 + kg * 4;
    const f32x4 bv = *(const f32x4*)(bh + h);

    uint16_t* wb = comm + (size_t)b * HID + h;      // publish/clear base
    float* ob = out + (size_t)b * HID + h;

    // staging geometry: thread covers frags f = i*256+tid, i=0..7;
    // LDS dst = Hb + f*16 (fragment order, lane-linear);
    // src = comm_slot + (grp*16 + (tid&15))*1024 + (tid>>6)*32 + ((tid>>4)&3)*8.
    const size_t ssrc = (size_t)(grp * NB + (tid & 15)) * HID
                      + ((tid >> 4) & 3) * 8 + (tid >> 6) * 32;

    u32x2 sentv; sentv.x = SENT; sentv.y = SENT;

    for (int t = 0; t < T_STEPS; ++t) {
        f32x4 ac0 = {0.f,0.f,0.f,0.f}, ac1 = {0.f,0.f,0.f,0.f};
        f32x4 ac2 = {0.f,0.f,0.f,0.f}, ac3 = {0.f,0.f,0.f,0.f};

        // ---- Phase A: X projection from reg-resident W_ih frags ----
        const float* xrow = X + ((size_t)t * BATCH + b) * IN_DIM;
        {
            f32x4 f0 = *(const f32x4*)(xrow + kg * 8);
            f32x4 f1 = *(const f32x4*)(xrow + kg * 8 + 4);
            ac0 = MFMA16(wreg[32], pack_bf16x8(f0, f1), ac0, 0, 0, 0);
            f0 = *(const f32x4*)(xrow + 32 + kg * 8);
            f1 = *(const f32x4*)(xrow + 32 + kg * 8 + 4);
            ac1 = MFMA16(wreg[33], pack_bf16x8(f0, f1), ac1, 0, 0, 0);
            f0 = *(const f32x4*)(xrow + 64 + kg * 8);
            f1 = *(const f32x4*)(xrow + 64 + kg * 8 + 4);
            ac2 = MFMA16(wreg[34], pack_bf16x8(f0, f1), ac2, 0, 0, 0);
            f0 = *(const f32x4*)(xrow + 96 + kg * 8);
            f1 = *(const f32x4*)(xrow + 96 + kg * 8 + 4);
            ac3 = MFMA16(wreg[35], pack_bf16x8(f0, f1), ac3, 0, 0, 0);
        }
        __builtin_amdgcn_sched_barrier(0);

        // ---- Phase B+C fused: ping-pong 2-set data poll of my 128 B portion.
        // vmcnt counts are exact: queue drained before first issue.
        char* Hb = lds + (size_t)(t & 1) * HBUF;
        const char* gsrc = (const char*)(comm + (size_t)(t & (RING - 1)) * SLOT
                                         + ssrc);
        f32x4 LA[8], LB[8];
        asm volatile("s_waitcnt vmcnt(0)" ::: "memory");  // drain stores/X
        __builtin_amdgcn_sched_barrier(0);
        ISSUE8(LA, gsrc);
        ISSUE8(LB, gsrc);
        bool fromA;
        for (;;) {
            asm volatile("s_waitcnt vmcnt(8)" ::: "memory");  // older set done
            __builtin_amdgcn_sched_barrier(0);
            int m;
            SCAN8(LA, m)
            if (__all(m != (int)SENT)) { fromA = true; break; }
            ISSUE8(LA, gsrc);
            asm volatile("s_waitcnt vmcnt(8)" ::: "memory");
            __builtin_amdgcn_sched_barrier(0);
            SCAN8(LB, m)
            if (__all(m != (int)SENT)) { fromA = false; break; }
            ISSUE8(LB, gsrc);
        }
        asm volatile("s_waitcnt vmcnt(0)" ::: "memory");  // retire loser set
        __builtin_amdgcn_sched_barrier(0);
        if (fromA) {
            #pragma unroll
            for (int i = 0; i < 8; ++i)
                *(f32x4*)(Hb + tid * 16 + i * 4096) = LA[i];
        } else {
            #pragma unroll
            for (int i = 0; i < 8; ++i)
                *(f32x4*)(Hb + tid * 16 + i * 4096) = LB[i];
        }
        {   // clear-ahead hoisted: retires under the MFMA block
            uint16_t* pc = wb + (size_t)((t + 1 + DCLR) & (RING - 1)) * SLOT;
            asm volatile("global_store_dwordx2 %0, %1, off sc0 sc1"
                         :: "v"(pc), "v"(sentv) : "memory");
        }
        __syncthreads();                 // H tile ready (double-buffered)

        // ---- recurrent GEMM: K=1024; A=W regs, B=H frags from LDS ----
        const char* hfb = Hb + lane * 16;
        #pragma unroll
        for (int kk = 0; kk < NKH; kk += 4) {
            s16x8 af0 = *(const s16x8*)(hfb + (size_t)(kk + 0) * 1024);
            s16x8 af1 = *(const s16x8*)(hfb + (size_t)(kk + 1) * 1024);
            s16x8 af2 = *(const s16x8*)(hfb + (size_t)(kk + 2) * 1024);
            s16x8 af3 = *(const s16x8*)(hfb + (size_t)(kk + 3) * 1024);
            ac0 = MFMA16(wreg[kk + 0], af0, ac0, 0, 0, 0);
            ac1 = MFMA16(wreg[kk + 1], af1, ac1, 0, 0, 0);
            ac2 = MFMA16(wreg[kk + 2], af2, ac2, 0, 0, 0);
            ac3 = MFMA16(wreg[kk + 3], af3, ac3, 0, 0, 0);
        }

        // ---- Epilogue: bias+tanh; publish 8B (no flag, no drain); out ----
        float t0 = tanh_fast(ac0[0] + ac1[0] + ac2[0] + ac3[0] + bv.x);
        float t1 = tanh_fast(ac0[1] + ac1[1] + ac2[1] + ac3[1] + bv.y);
        float t2 = tanh_fast(ac0[2] + ac1[2] + ac2[2] + ac3[2] + bv.z);
        float t3 = tanh_fast(ac0[3] + ac1[3] + ac2[3] + ac3[3] + bv.w);

        u32x2 cd;
        cd.x = cvt_pk_bf16(t0, t1);
        cd.y = cvt_pk_bf16(t2, t3);
        uint16_t* pw = wb + (size_t)((t + 1) & (RING - 1)) * SLOT;
        asm volatile("global_store_dwordx2 %0, %1, off sc0 sc1"
                     :: "v"(pw), "v"(cd) : "memory");

        // fp32 states (normal cached 16B store, off the critical path)
        f32x4 vo; vo.x = t0; vo.y = t1; vo.z = t2; vo.w = t3;
        *(f32x4*)(ob + (size_t)t * BATCH * HID) = vo;
        if (t == T_STEPS - 1)
            *(f32x4*)(ob + (size_t)T_STEPS * BATCH * HID) = vo;  // H_final
    }
}

extern "C" void kernel_launch(void* const* d_in, const int* in_sizes, int n_in,
                              void* d_out, int out_size, void* d_ws, size_t ws_size,
                              hipStream_t stream) {
    (void)in_sizes; (void)n_in; (void)out_size; (void)ws_size;
    const float* X   = (const float*)d_in[0];
    const float* Wih = (const float*)d_in[1];
    const float* Whh = (const float*)d_in[2];
    const float* bh  = (const float*)d_in[3];
    const float* H0  = (const float*)d_in[4];
    float* out = (float*)d_out;

    uint16_t* comm = (uint16_t*)d_ws;    // RING * SLOT bf16 = 2 MB

    hipFuncSetAttribute((const void*)rnn_seq_kernel,
                        hipFuncAttributeMaxDynamicSharedMemorySize, LDSB);

    // sentinel-fill the ring, then bf16(H0) -> slot 0
    hipMemsetAsync(comm, 0x7F, (size_t)RING * SLOT * 2, stream);
    hipLaunchKernelGGL(rnn_init_kernel, dim3(64), dim3(256), 0, stream, H0, comm);
    hipLaunchKernelGGL(rnn_seq_kernel, dim3(NGRP * NSL), dim3(THREADS), LDSB, stream,
                       X, Wih, Whh, bh, out, comm);
}

// Round 15
// 1834.544 us; speedup vs baseline: 1.1821x; 1.1821x over previous
//
#include <hip/hip_runtime.h>
#include <hip/hip_bf16.h>
#include <stdint.h>

// Problem constants
#define T_STEPS 512
#define BATCH   64
#define IN_DIM  128
#define HID     1024
#define KTOT    (HID + IN_DIM)   // 1152
#define NWAVES  4
#define THREADS (NWAVES * 64)

// 4 independent batch-groups x 16 col-slices. WG = 16 batches x 64 cols.
// Wave w: 16 batches x 16 cols, W in VGPRs (36 frags = 144 regs).
// Group H tile (16 x 1024 bf16 = 32 KB) double-buffered in LDS, shared.
// Detection: 1 probe/lane (64 probes cover the 64 producer-wave publishes,
// each of which is a single store instruction), then one staged load with
// sentinel validation as the correctness backstop.
#define NGRP    4
#define NSL     16               // col-slice WGs per group
#define NB      16               // batches per group
#define NKH     32               // recurrent K-steps (1024/32)
#define HBUF    32768            // one H LDS buffer
#define LDSB    73728            // W-stage scratch (also covers 2x32KB H)

#define RING    16               // comm ring slots (2 MB)
#define DCLR    4                // clear-ahead depth
#define SLOT    (BATCH * HID)    // 65536 bf16 = 128 KB per slot
#define SENT    0x7F7F7F7F      // bf16 pair 3.39e38, unreachable by tanh

typedef float f32x4 __attribute__((ext_vector_type(4)));
typedef int   i32x4 __attribute__((ext_vector_type(4)));
typedef short s16x8 __attribute__((ext_vector_type(8)));
typedef uint32_t u32x2 __attribute__((ext_vector_type(2)));

#define MFMA16 __builtin_amdgcn_mfma_f32_16x16x32_bf16

__device__ __forceinline__ uint32_t cvt_pk_bf16(float a, float b) {
    uint32_t r;
    asm("v_cvt_pk_bf16_f32 %0, %1, %2" : "=v"(r) : "v"(a), "v"(b));
    return r;   // low16 = bf16(a), high16 = bf16(b)
}

union frag_u { uint32_t u[4]; s16x8 s; };

__device__ __forceinline__ s16x8 pack_bf16x8(f32x4 a, f32x4 b) {
    frag_u f;
    f.u[0] = cvt_pk_bf16(a.x, a.y);
    f.u[1] = cvt_pk_bf16(a.z, a.w);
    f.u[2] = cvt_pk_bf16(b.x, b.y);
    f.u[3] = cvt_pk_bf16(b.z, b.w);
    return f.s;
}

__device__ __forceinline__ uint16_t f32_to_bf16(float v) {
    uint32_t u = __builtin_bit_cast(uint32_t, v);
    return (uint16_t)((u + 0x7FFFu + ((u >> 16) & 1u)) >> 16);
}

// fast tanh: 1 - 2/(e^{2x}+1); saturates correctly for |x| large
__device__ __forceinline__ float tanh_fast(float x) {
    float e = __expf(2.0f * x);
    return 1.0f - 2.0f * __builtin_amdgcn_rcpf(e + 1.0f);
}

__device__ __forceinline__ int imax(int a, int b) { return a > b ? a : b; }
__device__ __forceinline__ int max4(f32x4 v) {
    i32x4 a = __builtin_bit_cast(i32x4, v);
    return imax(imax(a.x, a.y), imax(a.z, a.w));
}

__global__ void rnn_init_kernel(const float* __restrict__ H0,
                                uint16_t* __restrict__ comm) {
    // slot 0 of the ring holds bf16(H0), read by step t=0
    int i = blockIdx.x * 256 + threadIdx.x;
    for (int e = i; e < SLOT; e += 64 * 256)
        comm[e] = f32_to_bf16(H0[e]);
}

__global__ __launch_bounds__(THREADS, 1)
void rnn_seq_kernel(const float* __restrict__ X, const float* __restrict__ Wih,
                    const float* __restrict__ Whh, const float* __restrict__ bh,
                    float* __restrict__ out, uint16_t* __restrict__ comm)
{
    extern __shared__ char lds[];

    const int tid = threadIdx.x;
    const int grp = blockIdx.x >> 4;       // batch group 0..3
    const int p   = blockIdx.x & 15;       // col-slice 0..15
    const int lane = tid & 63, wv = tid >> 6;
    const int cb = lane & 15, kg = lane >> 4;
    const int hc0 = p * 64;                // WG's first col
    const int b   = grp * NB + cb;         // batch row this lane owns

    // ---- One-time: load this wave's W (16 cols x 1152) into 36 reg frags.
    // Two-phase LDS bounce (fragment order, lane-linear, bijective).
    s16x8 wreg[36];
    #pragma unroll
    for (int half = 0; half < 2; ++half) {
        for (int e = tid; e < 32 * KTOT; e += THREADS) {
            int c2 = e & 31;
            int k  = e >> 5;
            int hcol = hc0 + half * 32 + c2;
            float w = (k < HID) ? Whh[(size_t)k * HID + hcol]
                                : Wih[(size_t)(k - HID) * HID + hcol];
            uint32_t off = ((uint32_t)((c2 >> 4) * 36 + (k >> 5)) << 10)
                         + (((k >> 3) & 3) << 8) + ((c2 & 15) << 4) + ((k & 7) << 1);
            *(uint16_t*)(lds + off) = f32_to_bf16(w);
        }
        __syncthreads();
        if ((wv >> 1) == half) {
            const char* base = lds + (size_t)(wv & 1) * 36 * 1024 + lane * 16;
            #pragma unroll
            for (int kk = 0; kk < 36; ++kk)
                wreg[kk] = *(const s16x8*)(base + (size_t)kk * 1024);
        }
        __syncthreads();
    }

    // D = mfma(Wfrag, Hfrag): rows = h, cols = batch. Lane owns
    // h = hc0 + wv*16 + kg*4 + {0..3} of batch b.
    const int h = hc0 + wv * 16 + kg * 4;
    const f32x4 bv = *(const f32x4*)(bh + h);

    uint16_t* wb = comm + (size_t)b * HID + h;      // publish/clear base
    float* ob = out + (size_t)b * HID + h;

    // staging geometry: thread covers frags f = i*256+tid, i=0..7;
    // LDS dst = Hb + f*16 (fragment order, lane-linear);
    // src = comm_slot + (grp*16 + (tid&15))*1024 + (tid>>6)*32 + ((tid>>4)&3)*8.
    const size_t ssrc = (size_t)(grp * NB + (tid & 15)) * HID
                      + ((tid >> 4) & 3) * 8 + (tid >> 6) * 32;

    // probe address: lane l watches producer-wave (p'=l>>2, wv'=l&3), whose
    // entire 16x16 publish is ONE global_store_dwordx2 instruction. Probe 4B
    // at row (grp*16), col 64*(l>>2)+16*(l&3) of the slot.
    const size_t probe_off = (size_t)(grp * NB) * HID
                           + 64 * (lane >> 2) + 16 * (lane & 3);

    u32x2 sentv; sentv.x = SENT; sentv.y = SENT;

    for (int t = 0; t < T_STEPS; ++t) {
        f32x4 ac0 = {0.f,0.f,0.f,0.f}, ac1 = {0.f,0.f,0.f,0.f};
        f32x4 ac2 = {0.f,0.f,0.f,0.f}, ac3 = {0.f,0.f,0.f,0.f};

        // ---- Phase A: X projection from reg-resident W_ih frags ----
        const float* xrow = X + ((size_t)t * BATCH + b) * IN_DIM;
        {
            f32x4 f0 = *(const f32x4*)(xrow + kg * 8);
            f32x4 f1 = *(const f32x4*)(xrow + kg * 8 + 4);
            ac0 = MFMA16(wreg[32], pack_bf16x8(f0, f1), ac0, 0, 0, 0);
            f0 = *(const f32x4*)(xrow + 32 + kg * 8);
            f1 = *(const f32x4*)(xrow + 32 + kg * 8 + 4);
            ac1 = MFMA16(wreg[33], pack_bf16x8(f0, f1), ac1, 0, 0, 0);
            f0 = *(const f32x4*)(xrow + 64 + kg * 8);
            f1 = *(const f32x4*)(xrow + 64 + kg * 8 + 4);
            ac2 = MFMA16(wreg[34], pack_bf16x8(f0, f1), ac2, 0, 0, 0);
            f0 = *(const f32x4*)(xrow + 96 + kg * 8);
            f1 = *(const f32x4*)(xrow + 96 + kg * 8 + 4);
            ac3 = MFMA16(wreg[35], pack_bf16x8(f0, f1), ac3, 0, 0, 0);
        }
        __builtin_amdgcn_sched_barrier(0);

        // ---- Phase B: cheap probe detect (1 load/lane covers one
        //      producer-wave's single-instruction publish) ----
        const uint16_t* slot = comm + (size_t)(t & (RING - 1)) * SLOT;
        if (t > 0) {
            const uint16_t* pp = slot + probe_off;
            for (;;) {
                int f;
                asm volatile("global_load_dword %0, %1, off sc0 sc1\n\t"
                             "s_waitcnt vmcnt(0)"
                             : "=v"(f) : "v"(pp) : "memory");
                if (__all(f != (int)SENT)) break;
            }
        }
        __builtin_amdgcn_sched_barrier(0);

        // ---- Phase C: staged load of my 128 B portion + sentinel validate
        //      (backstop for probe/data lane-skew; retry is rare) ----
        char* Hb = lds + (size_t)(t & 1) * HBUF;
        const char* gsrc = (const char*)(slot + ssrc);
        f32x4 L[8];
        for (;;) {
            #pragma unroll
            for (int i = 0; i < 8; ++i)
                asm volatile("global_load_dwordx4 %0, %1, off sc0 sc1"
                             : "=v"(L[i]) : "v"(gsrc + (size_t)i * 256) : "memory");
            asm volatile("s_waitcnt vmcnt(0)" ::: "memory");
            __builtin_amdgcn_sched_barrier(0);
            int m = (int)0x80000000;
            #pragma unroll
            for (int i = 0; i < 8; ++i) m = imax(m, max4(L[i]));
            if (__all(m != (int)SENT)) break;
        }
        #pragma unroll
        for (int i = 0; i < 8; ++i)
            *(f32x4*)(Hb + tid * 16 + i * 4096) = L[i];
        {   // clear-ahead hoisted: retires under the MFMA block
            uint16_t* pc = wb + (size_t)((t + 1 + DCLR) & (RING - 1)) * SLOT;
            asm volatile("global_store_dwordx2 %0, %1, off sc0 sc1"
                         :: "v"(pc), "v"(sentv) : "memory");
        }
        __syncthreads();                 // H tile ready (double-buffered)

        // ---- recurrent GEMM: K=1024; A=W regs, B=H frags from LDS;
        //      4-deep accumulator interleave (1 wave/SIMD: no TLP to hide
        //      MFMA latency, so ILP must) ----
        const char* hfb = Hb + lane * 16;
        #pragma unroll
        for (int kk = 0; kk < NKH; kk += 4) {
            s16x8 af0 = *(const s16x8*)(hfb + (size_t)(kk + 0) * 1024);
            s16x8 af1 = *(const s16x8*)(hfb + (size_t)(kk + 1) * 1024);
            s16x8 af2 = *(const s16x8*)(hfb + (size_t)(kk + 2) * 1024);
            s16x8 af3 = *(const s16x8*)(hfb + (size_t)(kk + 3) * 1024);
            ac0 = MFMA16(wreg[kk + 0], af0, ac0, 0, 0, 0);
            ac1 = MFMA16(wreg[kk + 1], af1, ac1, 0, 0, 0);
            ac2 = MFMA16(wreg[kk + 2], af2, ac2, 0, 0, 0);
            ac3 = MFMA16(wreg[kk + 3], af3, ac3, 0, 0, 0);
        }

        // ---- Epilogue: bias+tanh; publish 8B (no flag, no drain); out ----
        float t0 = tanh_fast(ac0[0] + ac1[0] + ac2[0] + ac3[0] + bv.x);
        float t1 = tanh_fast(ac0[1] + ac1[1] + ac2[1] + ac3[1] + bv.y);
        float t2 = tanh_fast(ac0[2] + ac1[2] + ac2[2] + ac3[2] + bv.z);
        float t3 = tanh_fast(ac0[3] + ac1[3] + ac2[3] + ac3[3] + bv.w);

        u32x2 cd;
        cd.x = cvt_pk_bf16(t0, t1);
        cd.y = cvt_pk_bf16(t2, t3);
        uint16_t* pw = wb + (size_t)((t + 1) & (RING - 1)) * SLOT;
        asm volatile("global_store_dwordx2 %0, %1, off sc0 sc1"
                     :: "v"(pw), "v"(cd) : "memory");

        // fp32 states (normal cached 16B store, off the critical path)
        f32x4 vo; vo.x = t0; vo.y = t1; vo.z = t2; vo.w = t3;
        *(f32x4*)(ob + (size_t)t * BATCH * HID) = vo;
        if (t == T_STEPS - 1)
            *(f32x4*)(ob + (size_t)T_STEPS * BATCH * HID) = vo;  // H_final
    }
}

extern "C" void kernel_launch(void* const* d_in, const int* in_sizes, int n_in,
                              void* d_out, int out_size, void* d_ws, size_t ws_size,
                              hipStream_t stream) {
    (void)in_sizes; (void)n_in; (void)out_size; (void)ws_size;
    const float* X   = (const float*)d_in[0];
    const float* Wih = (const float*)d_in[1];
    const float* Whh = (const float*)d_in[2];
    const float* bh  = (const float*)d_in[3];
    const float* H0  = (const float*)d_in[4];
    float* out = (float*)d_out;

    uint16_t* comm = (uint16_t*)d_ws;    // RING * SLOT bf16 = 2 MB

    hipFuncSetAttribute((const void*)rnn_seq_kernel,
                        hipFuncAttributeMaxDynamicSharedMemorySize, LDSB);

    // sentinel-fill the ring, then bf16(H0) -> slot 0
    hipMemsetAsync(comm, 0x7F, (size_t)RING * SLOT * 2, stream);
    hipLaunchKernelGGL(rnn_init_kernel, dim3(64), dim3(256), 0, stream, H0, comm);
    hipLaunchKernelGGL(rnn_seq_kernel, dim3(NGRP * NSL), dim3(THREADS), LDSB, stream,
                       X, Wih, Whh, bh, out, comm);
}